// Round 8
// baseline (129.227 us; speedup 1.0000x reference)
//
#include <hip/hip_runtime.h>
#include <stdint.h>

// YOLO-style loss, faithful to the (buggy) reference _xyxy: center = w/S for both x and y.
// loss = (5*(xy+wh) + obj + 0.5*noobj) / 1024, summed over 1024*80*80 cells.
//
// R7: R6 with NT loads reverted to plain loads (single-variable change).
//  - NT reads on gfx950 measured at ~1-2 TB/s regardless of coalescing (R3/R4/R6:
//    R6 ran at exactly FETCH/dur = 1.0 TB/s). Never use NT reads here.
//  - Structure: coalesced pred -> LDS via register double-buffer (1 barrier/tile),
//    targ+mask register ping-pong, 40KB LDS -> 4 blocks/CU.
//  - R0/R1/R2 (3 structures, occ 19-56%) all pin at 4.72-4.75 TB/s aggregate read
//    with FETCH ~128MB (harness's 512MB fill between replays flushes ~half of L3).
//    If R7 also lands ~55us, that's 4 structures at the same ceiling -> roofline.

#define S_INV (1.0f / 80.0f)

typedef float f4 __attribute__((ext_vector_type(4)));
typedef int   i4 __attribute__((ext_vector_type(4)));

#define TILE 256   // groups per block-iteration (1 group = 4 cells per thread)

__global__ void zero_out_kernel(float* out) { out[0] = 0.0f; }

struct TM { f4 t0, t1, t2, t3; i4 m; };

__device__ __forceinline__ void load_tm(TM& tm, const f4* __restrict__ targ4,
                                        const i4* __restrict__ mask4, int gid) {
    tm.t0 = targ4[4 * gid + 0];
    tm.t1 = targ4[4 * gid + 1];
    tm.t2 = targ4[4 * gid + 2];
    tm.t3 = targ4[4 * gid + 3];
    tm.m  = mask4[gid];          // i4/lane, unit lane stride: fully coalesced
}

__device__ __forceinline__ float cell_loss(float px, float py, float pw, float ph, float pc,
                                           float tx, float ty, float tw, float th, int m)
{
    // _xyxy (faithful to reference bug: center is w/S for BOTH axes)
    float cp = pw * S_INV;
    float ct = tw * S_INV;
    float px1 = cp - 0.5f * pw, py1 = cp - 0.5f * ph;
    float px2 = cp + 0.5f * pw, py2 = cp + 0.5f * ph;
    float tx1 = ct - 0.5f * tw, ty1 = ct - 0.5f * th;
    float tx2 = ct + 0.5f * tw, ty2 = ct + 0.5f * th;

    float iw = fmaxf(fminf(px2, tx2) - fmaxf(px1, tx1), 0.0f);
    float ih = fmaxf(fminf(py2, ty2) - fmaxf(py1, ty1), 0.0f);
    float inter = iw * ih;
    float uni = pw * ph + tw * th - inter;
    float iou = inter / uni;

    float dx = px - tx, dy = py - ty;
    float sw = sqrtf(pw) - sqrtf(tw);
    float sh = sqrtf(ph) - sqrtf(th);
    float dobj = pc - iou;

    float obj_term = 5.0f * ((dx * dx + dy * dy) + (sw * sw + sh * sh)) + dobj * dobj;
    float noobj_term = 0.5f * pc * pc;
    return (m > 0) ? obj_term : noobj_term;
}

__device__ __forceinline__ float compute_tile(const f4* __restrict__ lbuf, const TM& tm, int t)
{
    // thread t's group is tile-local group t: pred f4s 5t..5t+4
    f4 p0 = lbuf[5 * t + 0], p1 = lbuf[5 * t + 1], p2 = lbuf[5 * t + 2];
    f4 p3 = lbuf[5 * t + 3], p4 = lbuf[5 * t + 4];
    float s = 0.0f;
    s += cell_loss(p0.x, p0.y, p0.z, p0.w, p1.x,
                   tm.t0.x, tm.t0.y, tm.t0.z, tm.t0.w, tm.m.x);
    s += cell_loss(p1.y, p1.z, p1.w, p2.x, p2.y,
                   tm.t1.x, tm.t1.y, tm.t1.z, tm.t1.w, tm.m.y);
    s += cell_loss(p2.z, p2.w, p3.x, p3.y, p3.z,
                   tm.t2.x, tm.t2.y, tm.t2.z, tm.t2.w, tm.m.z);
    s += cell_loss(p3.w, p4.x, p4.y, p4.z, p4.w,
                   tm.t3.x, tm.t3.y, tm.t3.z, tm.t3.w, tm.m.w);
    return s;
}

__global__ __launch_bounds__(256) void yolo_loss_kernel(
    const f4* __restrict__ pred4,
    const f4* __restrict__ targ4,
    const i4* __restrict__ mask4,
    float* __restrict__ out,
    int ntiles)
{
    __shared__ f4 buf[2][5 * TILE];   // 2 x 20 KB -> 4 blocks/CU

    const int t  = threadIdx.x;
    const int bid = blockIdx.x;
    const int nb  = gridDim.x;
    float acc = 0.0f;

    const int cnt = (ntiles - 1 - bid) / nb + 1;   // uniform within block

    // ---- prologue: tile0 ----
    {
        const f4* ps = pred4 + (size_t)bid * 5 * TILE;
        f4 P[5];
        #pragma unroll
        for (int i = 0; i < 5; ++i)
            P[i] = ps[i * TILE + t];   // 1024B/instr, full lines, coalesced
        #pragma unroll
        for (int i = 0; i < 5; ++i)
            buf[0][i * TILE + t] = P[i];
    }
    TM T;
    load_tm(T, targ4, mask4, bid * TILE + t);
    __syncthreads();

    int cur = 0;
    for (int j = 1; j < cnt; ++j) {
        const int tile = bid + j * nb;
        // issue next tile's loads (in flight during compute)
        const f4* ps = pred4 + (size_t)tile * 5 * TILE;
        f4 P[5];
        #pragma unroll
        for (int i = 0; i < 5; ++i)
            P[i] = ps[i * TILE + t];
        TM T2;
        load_tm(T2, targ4, mask4, tile * TILE + t);

        // compute current tile from LDS
        acc += compute_tile(&buf[cur][0], T, t);

        // land next tile (compiler inserts vmcnt wait on P/T2 deps)
        #pragma unroll
        for (int i = 0; i < 5; ++i)
            buf[cur ^ 1][i * TILE + t] = P[i];
        __syncthreads();   // covers write-visibility AND read-done for both buffers
        cur ^= 1;
        T = T2;
    }
    acc += compute_tile(&buf[cur][0], T, t);

    // wave (64-lane) shuffle reduction, one atomic per wave
    #pragma unroll
    for (int off = 32; off > 0; off >>= 1)
        acc += __shfl_down(acc, off, 64);
    if ((t & 63) == 0)
        atomicAdd(out, acc * (1.0f / 1024.0f));
}

extern "C" void kernel_launch(void* const* d_in, const int* in_sizes, int n_in,
                              void* d_out, int out_size, void* d_ws, size_t ws_size,
                              hipStream_t stream) {
    const f4* pred4 = (const f4*)d_in[0];   // [1024,80,80,5] f32
    const f4* targ4 = (const f4*)d_in[1];   // [1024,80,80,4] f32
    const i4* mask4 = (const i4*)d_in[2];   // [1024,80,80]   i32
    float* out = (float*)d_out;

    int ncells = in_sizes[2];               // 6,553,600
    int ntiles = ncells / (4 * TILE);       // 6400 tiles of 1024 cells

    zero_out_kernel<<<1, 1, 0, stream>>>(out);

    const int block = 256;
    const int grid = 2048;                  // 3-4 tiles per block, 4 blocks/CU resident
    yolo_loss_kernel<<<grid, block, 0, stream>>>(pred4, targ4, mask4, out, ntiles);
}

// Round 9
// 47.111 us; speedup vs baseline: 2.7430x; 2.7430x over previous
//
#include <hip/hip_runtime.h>
#include <stdint.h>

// YOLO-style loss, faithful to the (buggy) reference _xyxy: center = w/S for both x and y.
// loss = (5*(xy+wh) + obj + 0.5*noobj) / 1024, summed over 1024*80*80 cells.
//
// R8: eliminate same-address atomic contention (the variable that perfectly splits
// all prior rounds: per-block atomics -> 55-66us, per-wave atomics -> 127-129us;
// 8192 serialized same-line atomics ~= +74us, matching R5/R6/R7 exactly).
//  - Load structure = R2's (best measured, 55.2us): strided direct loads,
//    explicit register ping-pong (2 groups in flight), no LDS, no barriers.
//  - Reduction: block partials -> d_ws (no atomics), final 1-block kernel sums
//    2048 partials and writes d_out (replaces zero_out too).
//  - NT reads: avoid (R3/R4 regressions; R6==R7 showed NT wasn't R6's issue, but
//    NT never helped either).

#define S_INV (1.0f / 80.0f)

typedef float f4 __attribute__((ext_vector_type(4)));
typedef int   i4 __attribute__((ext_vector_type(4)));

struct Grp {
    f4 p0, p1, p2, p3, p4;   // 20 pred floats (4 cells x 5)
    f4 t0, t1, t2, t3;       // 16 targ floats (4 cells x 4)
    i4 m;                    // 4 mask ints
};

__device__ __forceinline__ void load_grp(Grp& g,
                                         const f4* __restrict__ pred4,
                                         const f4* __restrict__ targ4,
                                         const i4* __restrict__ mask4,
                                         int idx)
{
    g.p0 = pred4[5 * idx + 0];
    g.p1 = pred4[5 * idx + 1];
    g.p2 = pred4[5 * idx + 2];
    g.p3 = pred4[5 * idx + 3];
    g.p4 = pred4[5 * idx + 4];
    g.t0 = targ4[4 * idx + 0];
    g.t1 = targ4[4 * idx + 1];
    g.t2 = targ4[4 * idx + 2];
    g.t3 = targ4[4 * idx + 3];
    g.m  = mask4[idx];
}

__device__ __forceinline__ float cell_loss(float px, float py, float pw, float ph, float pc,
                                           float tx, float ty, float tw, float th, int m)
{
    // _xyxy (faithful to reference bug: center is w/S for BOTH axes)
    float cp = pw * S_INV;
    float ct = tw * S_INV;
    float px1 = cp - 0.5f * pw, py1 = cp - 0.5f * ph;
    float px2 = cp + 0.5f * pw, py2 = cp + 0.5f * ph;
    float tx1 = ct - 0.5f * tw, ty1 = ct - 0.5f * th;
    float tx2 = ct + 0.5f * tw, ty2 = ct + 0.5f * th;

    float iw = fmaxf(fminf(px2, tx2) - fmaxf(px1, tx1), 0.0f);
    float ih = fmaxf(fminf(py2, ty2) - fmaxf(py1, ty1), 0.0f);
    float inter = iw * ih;
    float uni = pw * ph + tw * th - inter;
    float iou = inter / uni;

    float dx = px - tx, dy = py - ty;
    float sw = sqrtf(pw) - sqrtf(tw);
    float sh = sqrtf(ph) - sqrtf(th);
    float dobj = pc - iou;

    float obj_term = 5.0f * ((dx * dx + dy * dy) + (sw * sw + sh * sh)) + dobj * dobj;
    float noobj_term = 0.5f * pc * pc;
    return (m > 0) ? obj_term : noobj_term;
}

__device__ __forceinline__ float compute_grp(const Grp& g)
{
    float s = 0.0f;
    s += cell_loss(g.p0.x, g.p0.y, g.p0.z, g.p0.w, g.p1.x,
                   g.t0.x, g.t0.y, g.t0.z, g.t0.w, g.m.x);
    s += cell_loss(g.p1.y, g.p1.z, g.p1.w, g.p2.x, g.p2.y,
                   g.t1.x, g.t1.y, g.t1.z, g.t1.w, g.m.y);
    s += cell_loss(g.p2.z, g.p2.w, g.p3.x, g.p3.y, g.p3.z,
                   g.t2.x, g.t2.y, g.t2.z, g.t2.w, g.m.z);
    s += cell_loss(g.p3.w, g.p4.x, g.p4.y, g.p4.z, g.p4.w,
                   g.t3.x, g.t3.y, g.t3.z, g.t3.w, g.m.w);
    return s;
}

__global__ __launch_bounds__(256) void yolo_loss_kernel(
    const f4* __restrict__ pred4,
    const f4* __restrict__ targ4,
    const i4* __restrict__ mask4,
    float* __restrict__ partials,
    int ngroups)
{
    float acc = 0.0f;
    int tid = blockIdx.x * blockDim.x + threadIdx.x;
    int stride = gridDim.x * blockDim.x;

    int g = tid;
    Grp A, B;
    bool haveA = (g < ngroups);
    if (haveA) load_grp(A, pred4, targ4, mask4, g);

    // software pipeline: loads for g2 are in flight while computing A
    #pragma unroll 2
    for (int g2 = g + stride; g2 < ngroups; g2 += stride) {
        load_grp(B, pred4, targ4, mask4, g2);
        acc += compute_grp(A);
        A = B;
    }
    if (haveA) acc += compute_grp(A);

    // wave (64-lane) shuffle reduction
    #pragma unroll
    for (int off = 32; off > 0; off >>= 1)
        acc += __shfl_down(acc, off, 64);

    __shared__ float wsum[4];
    int lane = threadIdx.x & 63;
    int wid = threadIdx.x >> 6;
    if (lane == 0) wsum[wid] = acc;
    __syncthreads();

    if (threadIdx.x == 0)
        partials[blockIdx.x] = wsum[0] + wsum[1] + wsum[2] + wsum[3];   // no atomics
}

__global__ __launch_bounds__(256) void final_reduce_kernel(
    const float* __restrict__ partials, float* __restrict__ out, int n)
{
    float a = 0.0f;
    for (int i = threadIdx.x; i < n; i += 256)
        a += partials[i];

    #pragma unroll
    for (int off = 32; off > 0; off >>= 1)
        a += __shfl_down(a, off, 64);

    __shared__ float wsum[4];
    int lane = threadIdx.x & 63;
    int wid = threadIdx.x >> 6;
    if (lane == 0) wsum[wid] = a;
    __syncthreads();

    if (threadIdx.x == 0)
        out[0] = (wsum[0] + wsum[1] + wsum[2] + wsum[3]) * (1.0f / 1024.0f);
}

extern "C" void kernel_launch(void* const* d_in, const int* in_sizes, int n_in,
                              void* d_out, int out_size, void* d_ws, size_t ws_size,
                              hipStream_t stream) {
    const f4* pred4 = (const f4*)d_in[0];   // [1024,80,80,5] f32
    const f4* targ4 = (const f4*)d_in[1];   // [1024,80,80,4] f32
    const i4* mask4 = (const i4*)d_in[2];   // [1024,80,80]   i32
    float* out = (float*)d_out;
    float* partials = (float*)d_ws;         // 2048 floats = 8 KB

    int ncells = in_sizes[2];            // 1024*80*80 = 6,553,600
    int ngroups = ncells / 4;            // 1,638,400

    const int block = 256;
    const int grid = 2048;               // each block writes exactly one partial
    yolo_loss_kernel<<<grid, block, 0, stream>>>(pred4, targ4, mask4, partials, ngroups);
    final_reduce_kernel<<<1, block, 0, stream>>>(partials, out, grid);
}